// Round 4
// baseline (2181.977 us; speedup 1.0000x reference)
//
#include <hip/hip_runtime.h>
#include <cstdint>

#define Eexp 8
#define Bb   16384
#define Dd   512
#define Hh   512
#define Zz   64

typedef _Float16 f16x8  __attribute__((ext_vector_type(8)));
typedef _Float16 f16x4  __attribute__((ext_vector_type(4)));
typedef float    f32x16 __attribute__((ext_vector_type(16)));

// per-expert transposed-split weight region (elements), fixed layout
#define PEREXP     1671168
#define OFF_ENCIN  0
#define OFF_HID0   262144
#define OFF_HID1   524288
#define OFF_MU     786432
#define OFF_LV     819200
#define OFF_DECIN  851968
#define OFF_DHID0  884736
#define OFF_DHID1  1146880
#define OFF_DECOUT 1409024
#define WT_ELEMS   (8 * (size_t)PEREXP)

#define GLL16(g, l) __builtin_amdgcn_global_load_lds( \
    (const __attribute__((address_space(1))) void*)(g), \
    (__attribute__((address_space(3))) void*)(l), 16, 0, 0)

// ---------------------------------------------------------------------------
// Weight transpose + f16 hi/lo split:  src[K,N] fp32 -> dst[N,K] f16 (hi,lo)
// ---------------------------------------------------------------------------
__global__ __launch_bounds__(256)
void tsplit(const float* __restrict__ src, _Float16* __restrict__ dH,
            _Float16* __restrict__ dL, int K, int N, long sStride, long dStride)
{
    __shared__ float t[64][65];
    const int e  = blockIdx.z;
    const int n0 = blockIdx.x * 64, k0 = blockIdx.y * 64;
    const float* S = src + (size_t)e * sStride;
    const int tid = threadIdx.x;
    const int rr = tid >> 4, cc = (tid & 15) * 4;
    #pragma unroll
    for (int p = 0; p < 4; ++p) {
        const float4 v = *reinterpret_cast<const float4*>(
            &S[(size_t)(k0 + rr + p * 16) * N + n0 + cc]);
        t[rr + p * 16][cc + 0] = v.x; t[rr + p * 16][cc + 1] = v.y;
        t[rr + p * 16][cc + 2] = v.z; t[rr + p * 16][cc + 3] = v.w;
    }
    __syncthreads();
    _Float16* DH = dH + (size_t)e * dStride;
    _Float16* DL = dL + (size_t)e * dStride;
    #pragma unroll
    for (int p = 0; p < 4; ++p) {
        const int no = rr + p * 16;
        const float a = t[cc + 0][no], b = t[cc + 1][no];
        const float c = t[cc + 2][no], d = t[cc + 3][no];
        const _Float16 ha = (_Float16)a, hb = (_Float16)b;
        const _Float16 hc = (_Float16)c, hd = (_Float16)d;
        f16x4 hv = {ha, hb, hc, hd};
        f16x4 lv = {(_Float16)(a - (float)ha), (_Float16)(b - (float)hb),
                    (_Float16)(c - (float)hc), (_Float16)(d - (float)hd)};
        *reinterpret_cast<f16x4*>(&DH[(size_t)(n0 + no) * K + k0 + cc]) = hv;
        *reinterpret_cast<f16x4*>(&DL[(size_t)(n0 + no) * K + k0 + cc]) = lv;
    }
}

// fp32 -> f16 hi/lo planes (for x)
__global__ __launch_bounds__(256)
void xsplit(const float4* __restrict__ src, f16x4* __restrict__ dh,
            f16x4* __restrict__ dl)
{
    const int i = blockIdx.x * 256 + threadIdx.x;
    const float4 v = src[i];
    const _Float16 h0 = (_Float16)v.x, h1 = (_Float16)v.y;
    const _Float16 h2 = (_Float16)v.z, h3 = (_Float16)v.w;
    f16x4 hv = {h0, h1, h2, h3};
    f16x4 lv = {(_Float16)(v.x - (float)h0), (_Float16)(v.y - (float)h1),
                (_Float16)(v.z - (float)h2), (_Float16)(v.w - (float)h3)};
    dh[i] = hv; dl[i] = lv;
}

// ---------------------------------------------------------------------------
// Split-f16 MFMA GEMM, 32x32x16 frags, double-buffered LDS pipeline:
//   stage(t+1) -> ds_read/MFMA(t) -> vmcnt(0) -> barrier
// A planes [M,Ka] f16 (hi/lo), W planes [N,Ka] f16. BM=128, BK=32, 4 waves 2x2,
// wave tile 64 x (BN/2). 16B-slot XOR swizzle: slot ^= (row>>1)&3.
// MODE 0: relu + split-f16 out   MODE 1: fp32 out + fused per-row SSE partials
// MODE 2: dual fp32 out (mu/lv via grid-half)
// ---------------------------------------------------------------------------
template<int BN, int MODE>
__global__ __launch_bounds__(256, 2)
void gemm_sp(const _Float16* __restrict__ Ah, const _Float16* __restrict__ Al,
             const _Float16* __restrict__ Wh0, const _Float16* __restrict__ Wl0,
             const float* __restrict__ bias0,
             float* __restrict__ Cf0, _Float16* __restrict__ Ch0,
             _Float16* __restrict__ Cl0,
             const _Float16* __restrict__ Wh1, const _Float16* __restrict__ Wl1,
             const float* __restrict__ bias1, float* __restrict__ Cf1,
             const float* __restrict__ Xin, float* __restrict__ rec8,
             int Ka, int Nout)
{
    constexpr int BM = 128, BK = 32;
    constexpr int WN = BN / 2;        // 64 or 32
    constexpr int NF = WN / 32;       // 2 or 1
    constexpr int CPW = BN / 64;      // W chunks per wave per plane
    __shared__ __align__(16) _Float16 sA[2][2][BM * BK];
    __shared__ __align__(16) _Float16 sW[2][2][BN * BK];

    const int nY = (MODE == 2) ? 2 : (Nout / BN);
    int wg = blockIdx.x;
    wg = (wg & 7) * (gridDim.x >> 3) + (wg >> 3);
    const int bx = wg / nY;
    const int by = wg % nY;

    const _Float16* WhP = Wh0; const _Float16* WlP = Wl0;
    const float* biasP = bias0; float* CfP = Cf0;
    if (MODE == 2 && by == 1) { WhP = Wh1; WlP = Wl1; biasP = bias1; CfP = Cf1; }

    const int tid  = threadIdx.x;
    const int lane = tid & 63;
    const int wid  = tid >> 6;
    const int wr = wid >> 1, wc = wid & 1;
    const int row0 = bx * BM;
    const int col0 = (MODE == 2) ? 0 : by * BN;

    f32x16 acc[2][NF];
    #pragma unroll
    for (int i = 0; i < 2; ++i)
        #pragma unroll
        for (int j = 0; j < NF; ++j)
            #pragma unroll
            for (int r = 0; r < 16; ++r) acc[i][j][r] = 0.f;

    // staging lane map (shared by A and W chunks)
    const int clane = lane >> 2;           // row within 16-row chunk
    const int cslot = lane & 3;

    #define STAGE(buf, k0)                                                  \
    {                                                                       \
        _Pragma("unroll")                                                   \
        for (int p = 0; p < 2; ++p) {                                       \
            const int q  = wid * 2 + p;                                     \
            const int rl = q * 16 + clane;                                  \
            const int c  = cslot ^ ((rl >> 1) & 3);                         \
            const size_t gi = (size_t)(row0 + rl) * Ka + (k0) + c * 8;      \
            GLL16(Ah + gi, &sA[buf][0][q * 512]);                           \
            GLL16(Al + gi, &sA[buf][1][q * 512]);                           \
        }                                                                   \
        _Pragma("unroll")                                                   \
        for (int p = 0; p < CPW; ++p) {                                     \
            const int q  = wid * CPW + p;                                   \
            const int rl = q * 16 + clane;                                  \
            const int c  = cslot ^ ((rl >> 1) & 3);                         \
            const size_t gi = (size_t)(col0 + rl) * Ka + (k0) + c * 8;      \
            GLL16(WhP + gi, &sW[buf][0][q * 512]);                          \
            GLL16(WlP + gi, &sW[buf][1][q * 512]);                          \
        }                                                                   \
    }

    STAGE(0, 0)
    asm volatile("s_waitcnt vmcnt(0)" ::: "memory");
    __builtin_amdgcn_s_barrier();

    const int NT = Ka / BK;
    int cur = 0;
    for (int t = 0; t < NT; ++t) {
        if (t + 1 < NT) STAGE(cur ^ 1, (t + 1) * BK)

        #pragma unroll
        for (int kk = 0; kk < 2; ++kk) {
            f16x8 fah[2], fal[2], fwh[NF], fwl[NF];
            #pragma unroll
            for (int mf = 0; mf < 2; ++mf) {
                const int r = wr * 64 + mf * 32 + (lane & 31);
                const int u = ((lane >> 5) + 2 * kk) ^ ((r >> 1) & 3);
                fah[mf] = *reinterpret_cast<f16x8*>(&sA[cur][0][r * 32 + u * 8]);
                fal[mf] = *reinterpret_cast<f16x8*>(&sA[cur][1][r * 32 + u * 8]);
            }
            #pragma unroll
            for (int nf = 0; nf < NF; ++nf) {
                const int r = wc * WN + nf * 32 + (lane & 31);
                const int u = ((lane >> 5) + 2 * kk) ^ ((r >> 1) & 3);
                fwh[nf] = *reinterpret_cast<f16x8*>(&sW[cur][0][r * 32 + u * 8]);
                fwl[nf] = *reinterpret_cast<f16x8*>(&sW[cur][1][r * 32 + u * 8]);
            }
            __builtin_amdgcn_s_setprio(1);
            #pragma unroll
            for (int mf = 0; mf < 2; ++mf)
                #pragma unroll
                for (int nf = 0; nf < NF; ++nf) {
                    acc[mf][nf] = __builtin_amdgcn_mfma_f32_32x32x16_f16(
                        fah[mf], fwh[nf], acc[mf][nf], 0, 0, 0);
                    acc[mf][nf] = __builtin_amdgcn_mfma_f32_32x32x16_f16(
                        fah[mf], fwl[nf], acc[mf][nf], 0, 0, 0);
                    acc[mf][nf] = __builtin_amdgcn_mfma_f32_32x32x16_f16(
                        fal[mf], fwh[nf], acc[mf][nf], 0, 0, 0);
                }
            __builtin_amdgcn_s_setprio(0);
        }
        asm volatile("s_waitcnt vmcnt(0)" ::: "memory");
        __builtin_amdgcn_s_barrier();
        cur ^= 1;
    }
    #undef STAGE

    // ---- epilogue ----
    #pragma unroll
    for (int nf = 0; nf < NF; ++nf) {
        const int col = col0 + wc * WN + nf * 32 + (lane & 31);
        const float bv = biasP[col];
        #pragma unroll
        for (int mf = 0; mf < 2; ++mf) {
            float sse[16];
            #pragma unroll
            for (int rg = 0; rg < 16; ++rg) {
                const int rloc = (rg & 3) + 8 * (rg >> 2) + 4 * (lane >> 5);
                const int rowg = row0 + wr * 64 + mf * 32 + rloc;
                float v = acc[mf][nf][rg] + bv;
                if (MODE == 0) {
                    v = fmaxf(v, 0.f);
                    const _Float16 h = (_Float16)v;
                    const _Float16 l = (_Float16)(v - (float)h);
                    Ch0[(size_t)rowg * Nout + col] = h;
                    Cl0[(size_t)rowg * Nout + col] = l;
                } else {
                    CfP[(size_t)rowg * Nout + col] = v;
                    if (MODE == 1) {
                        const float d = v - Xin[(size_t)rowg * Nout + col];
                        sse[rg] = d * d;
                    }
                }
            }
            if (MODE == 1) {
                // per-row reduce over the 32 lanes of this half-wave
                #pragma unroll
                for (int rg = 0; rg < 16; ++rg) {
                    float s = sse[rg];
                    #pragma unroll
                    for (int m = 1; m < 32; m <<= 1) s += __shfl_xor(s, m);
                    if ((lane & 31) == 0) {
                        const int rloc = (rg & 3) + 8 * (rg >> 2) + 4 * (lane >> 5);
                        const int rowg = row0 + wr * 64 + mf * 32 + rloc;
                        if (nf == 0)
                            rec8[(size_t)(by * 2 + wc) * Bb + rowg] = s;
                        else
                            rec8[(size_t)(by * 2 + wc) * Bb + rowg] += s;
                    }
                }
            }
        }
    }
}

// z = mu + exp(0.5*logvar)*eps -> split f16 planes; also zeroes rec8
__global__ __launch_bounds__(256)
void z_kernel(const float4* __restrict__ mu, const float4* __restrict__ lv,
              const float4* __restrict__ eps, f16x4* __restrict__ zh,
              f16x4* __restrict__ zl, float* __restrict__ rec8)
{
    const int i = blockIdx.x * 256 + threadIdx.x;
    if (i < Eexp * Bb) rec8[i] = 0.f;
    const float4 m = mu[i], l = lv[i], e = eps[i];
    float4 r;
    r.x = m.x + expf(0.5f * l.x) * e.x;
    r.y = m.y + expf(0.5f * l.y) * e.y;
    r.z = m.z + expf(0.5f * l.z) * e.z;
    r.w = m.w + expf(0.5f * l.w) * e.w;
    const _Float16 h0 = (_Float16)r.x, h1 = (_Float16)r.y;
    const _Float16 h2 = (_Float16)r.z, h3 = (_Float16)r.w;
    f16x4 hv = {h0, h1, h2, h3};
    f16x4 lvv = {(_Float16)(r.x - (float)h0), (_Float16)(r.y - (float)h1),
                 (_Float16)(r.z - (float)h2), (_Float16)(r.w - (float)h3)};
    zh[i] = hv; zl[i] = lvv;
}

// sum rec8 partials, running-min select + gather
__global__ __launch_bounds__(256)
void select_kernel(const float* __restrict__ rec8, float* __restrict__ best,
                   const float* __restrict__ mu_e, const float* __restrict__ lv_e,
                   const float* __restrict__ xhat,
                   float* __restrict__ out_mu, float* __restrict__ out_lv,
                   float* __restrict__ out_xh, int isFirst)
{
    const int wave = threadIdx.x >> 6;
    const int lane = threadIdx.x & 63;
    const int row  = blockIdx.x * 4 + wave;
    float r = 0.f;
    #pragma unroll
    for (int p = 0; p < 8; ++p) r += rec8[(size_t)p * Bb + row];
    r *= (1.0f / 512.0f);
    const bool cond = isFirst || (r < best[row]);
    if (cond) {
        if (lane == 0) best[row] = r;
        out_mu[(size_t)row * Zz + lane] = mu_e[(size_t)row * Zz + lane];
        out_lv[(size_t)row * Zz + lane] = lv_e[(size_t)row * Zz + lane];
        const float4* src = reinterpret_cast<const float4*>(&xhat[(size_t)row * Dd]);
        float4*       dst = reinterpret_cast<float4*>(&out_xh[(size_t)row * Dd]);
        dst[lane]      = src[lane];
        dst[lane + 64] = src[lane + 64];
    }
}

extern "C" void kernel_launch(void* const* d_in, const int* in_sizes, int n_in,
                              void* d_out, int out_size, void* d_ws, size_t ws_size,
                              hipStream_t stream)
{
    const float* x         = (const float*)d_in[0];
    const float* eps       = (const float*)d_in[1];
    const float* enc_in_w  = (const float*)d_in[2];
    const float* enc_in_b  = (const float*)d_in[3];
    const float* enc_hid_w = (const float*)d_in[4];
    const float* enc_hid_b = (const float*)d_in[5];
    const float* mu_w      = (const float*)d_in[6];
    const float* mu_b      = (const float*)d_in[7];
    const float* lv_w      = (const float*)d_in[8];
    const float* lv_b      = (const float*)d_in[9];
    const float* dec_in_w  = (const float*)d_in[10];
    const float* dec_in_b  = (const float*)d_in[11];
    const float* dec_hid_w = (const float*)d_in[12];
    const float* dec_hid_b = (const float*)d_in[13];
    const float* dec_out_w = (const float*)d_in[14];
    const float* dec_out_b = (const float*)d_in[15];

    const size_t BD = (size_t)Bb * 512;
    const size_t BZ = (size_t)Bb * 64;

    _Float16* wtH = (_Float16*)d_ws;
    _Float16* wtL = wtH + WT_ELEMS;
    _Float16* xh  = wtL + WT_ELEMS;
    _Float16* xl  = xh + BD;
    _Float16* aH  = xl + BD;
    _Float16* aL  = aH + BD;
    _Float16* bH  = aL + BD;
    _Float16* bL  = bH + BD;
    _Float16* zh  = bL + BD;
    _Float16* zl  = zh + BZ;
    float* fbase  = (float*)(zl + BZ);
    float* xhat   = fbase;                 // [B,512] fp32
    float* mu_e   = xhat + BD;
    float* lv_e   = mu_e + BZ;
    float* rec8   = lv_e + BZ;             // [8,B]
    float* best   = rec8 + (size_t)Eexp * Bb;

    float* out_mu = (float*)d_out;
    float* out_lv = out_mu + (size_t)Bb * Zz;
    float* out_xh = out_lv + (size_t)Bb * Zz;

    const dim3 blk(256);

    tsplit<<<dim3(8, 8, 8), blk, 0, stream>>>(enc_in_w,           wtH + OFF_ENCIN,  wtL + OFF_ENCIN,  512, 512, 262144, PEREXP);
    tsplit<<<dim3(8, 8, 8), blk, 0, stream>>>(enc_hid_w,          wtH + OFF_HID0,   wtL + OFF_HID0,   512, 512, 524288, PEREXP);
    tsplit<<<dim3(8, 8, 8), blk, 0, stream>>>(enc_hid_w + 262144, wtH + OFF_HID1,   wtL + OFF_HID1,   512, 512, 524288, PEREXP);
    tsplit<<<dim3(1, 8, 8), blk, 0, stream>>>(mu_w,               wtH + OFF_MU,     wtL + OFF_MU,     512,  64,  32768, PEREXP);
    tsplit<<<dim3(1, 8, 8), blk, 0, stream>>>(lv_w,               wtH + OFF_LV,     wtL + OFF_LV,     512,  64,  32768, PEREXP);
    tsplit<<<dim3(8, 1, 8), blk, 0, stream>>>(dec_in_w,           wtH + OFF_DECIN,  wtL + OFF_DECIN,   64, 512,  32768, PEREXP);
    tsplit<<<dim3(8, 8, 8), blk, 0, stream>>>(dec_hid_w,          wtH + OFF_DHID0,  wtL + OFF_DHID0,  512, 512, 524288, PEREXP);
    tsplit<<<dim3(8, 8, 8), blk, 0, stream>>>(dec_hid_w + 262144, wtH + OFF_DHID1,  wtL + OFF_DHID1,  512, 512, 524288, PEREXP);
    tsplit<<<dim3(8, 8, 8), blk, 0, stream>>>(dec_out_w,          wtH + OFF_DECOUT, wtL + OFF_DECOUT, 512, 512, 262144, PEREXP);
    xsplit<<<dim3(BD / 4 / 256), blk, 0, stream>>>(
        (const float4*)x, (f16x4*)xh, (f16x4*)xl);

    const dim3 gBig(512);
    const dim3 gDual(256);
    const dim3 gRow(Bb / 4);
    const dim3 gZ(BZ / 4 / 256);

    for (int e = 0; e < Eexp; ++e) {
        const size_t wo = (size_t)e * PEREXP;
        gemm_sp<128, 0><<<gBig, blk, 0, stream>>>(
            xh, xl, wtH + wo + OFF_ENCIN, wtL + wo + OFF_ENCIN,
            enc_in_b + (size_t)e * Hh, nullptr, aH, aL,
            nullptr, nullptr, nullptr, nullptr, nullptr, nullptr, Dd, Hh);
        gemm_sp<128, 0><<<gBig, blk, 0, stream>>>(
            aH, aL, wtH + wo + OFF_HID0, wtL + wo + OFF_HID0,
            enc_hid_b + ((size_t)e * 2 + 0) * Hh, nullptr, bH, bL,
            nullptr, nullptr, nullptr, nullptr, nullptr, nullptr, Hh, Hh);
        gemm_sp<128, 0><<<gBig, blk, 0, stream>>>(
            bH, bL, wtH + wo + OFF_HID1, wtL + wo + OFF_HID1,
            enc_hid_b + ((size_t)e * 2 + 1) * Hh, nullptr, aH, aL,
            nullptr, nullptr, nullptr, nullptr, nullptr, nullptr, Hh, Hh);
        gemm_sp<64, 2><<<gDual, blk, 0, stream>>>(
            aH, aL, wtH + wo + OFF_MU, wtL + wo + OFF_MU,
            mu_b + (size_t)e * Zz, mu_e, nullptr, nullptr,
            wtH + wo + OFF_LV, wtL + wo + OFF_LV,
            lv_b + (size_t)e * Zz, lv_e, nullptr, nullptr, Hh, Zz);
        z_kernel<<<gZ, blk, 0, stream>>>(
            (const float4*)mu_e, (const float4*)lv_e, (const float4*)eps,
            (f16x4*)zh, (f16x4*)zl, rec8);
        gemm_sp<128, 0><<<gBig, blk, 0, stream>>>(
            zh, zl, wtH + wo + OFF_DECIN, wtL + wo + OFF_DECIN,
            dec_in_b + (size_t)e * Hh, nullptr, bH, bL,
            nullptr, nullptr, nullptr, nullptr, nullptr, nullptr, Zz, Hh);
        gemm_sp<128, 0><<<gBig, blk, 0, stream>>>(
            bH, bL, wtH + wo + OFF_DHID0, wtL + wo + OFF_DHID0,
            dec_hid_b + ((size_t)e * 2 + 0) * Hh, nullptr, aH, aL,
            nullptr, nullptr, nullptr, nullptr, nullptr, nullptr, Hh, Hh);
        gemm_sp<128, 0><<<gBig, blk, 0, stream>>>(
            aH, aL, wtH + wo + OFF_DHID1, wtL + wo + OFF_DHID1,
            dec_hid_b + ((size_t)e * 2 + 1) * Hh, nullptr, bH, bL,
            nullptr, nullptr, nullptr, nullptr, nullptr, nullptr, Hh, Hh);
        gemm_sp<128, 1><<<gBig, blk, 0, stream>>>(
            bH, bL, wtH + wo + OFF_DECOUT, wtL + wo + OFF_DECOUT,
            dec_out_b + (size_t)e * Dd, xhat, nullptr, nullptr,
            nullptr, nullptr, nullptr, nullptr, x, rec8, Hh, Dd);
        select_kernel<<<gRow, blk, 0, stream>>>(
            rec8, best, mu_e, lv_e, xhat, out_mu, out_lv, out_xh, e == 0 ? 1 : 0);
    }
}

// Round 5
// 1889.068 us; speedup vs baseline: 1.1551x; 1.1551x over previous
//
#include <hip/hip_runtime.h>
#include <cstdint>

#define Eexp 8
#define Bb   16384
#define Dd   512
#define Hh   512
#define Zz   64

typedef _Float16 f16x8 __attribute__((ext_vector_type(8)));
typedef _Float16 f16x4 __attribute__((ext_vector_type(4)));
typedef float    f32x4 __attribute__((ext_vector_type(4)));

// per-expert transposed-split weight region (elements), fixed layout
#define PEREXP     1671168
#define OFF_ENCIN  0
#define OFF_HID0   262144
#define OFF_HID1   524288
#define OFF_MU     786432
#define OFF_LV     819200     /* contiguous after MU: rows 64..127 of the heads-W */
#define OFF_DECIN  851968
#define OFF_DHID0  884736
#define OFF_DHID1  1146880
#define OFF_DECOUT 1409024
#define WT_ELEMS   (8 * (size_t)PEREXP)

#define GLL16(g, l) __builtin_amdgcn_global_load_lds( \
    (const __attribute__((address_space(1))) void*)(g), \
    (__attribute__((address_space(3))) void*)(l), 16, 0, 0)

// ---------------------------------------------------------------------------
// Weight transpose + f16 hi/lo split:  src[K,N] fp32 -> dst[N,K] f16 (hi,lo)
// ---------------------------------------------------------------------------
__global__ __launch_bounds__(256)
void tsplit(const float* __restrict__ src, _Float16* __restrict__ dH,
            _Float16* __restrict__ dL, int K, int N, long sStride, long dStride)
{
    __shared__ float t[64][65];
    const int e  = blockIdx.z;
    const int n0 = blockIdx.x * 64, k0 = blockIdx.y * 64;
    const float* S = src + (size_t)e * sStride;
    const int tid = threadIdx.x;
    const int rr = tid >> 4, cc = (tid & 15) * 4;
    #pragma unroll
    for (int p = 0; p < 4; ++p) {
        const float4 v = *reinterpret_cast<const float4*>(
            &S[(size_t)(k0 + rr + p * 16) * N + n0 + cc]);
        t[rr + p * 16][cc + 0] = v.x; t[rr + p * 16][cc + 1] = v.y;
        t[rr + p * 16][cc + 2] = v.z; t[rr + p * 16][cc + 3] = v.w;
    }
    __syncthreads();
    _Float16* DH = dH + (size_t)e * dStride;
    _Float16* DL = dL + (size_t)e * dStride;
    #pragma unroll
    for (int p = 0; p < 4; ++p) {
        const int no = rr + p * 16;
        const float a = t[cc + 0][no], b = t[cc + 1][no];
        const float c = t[cc + 2][no], d = t[cc + 3][no];
        const _Float16 ha = (_Float16)a, hb = (_Float16)b;
        const _Float16 hc = (_Float16)c, hd = (_Float16)d;
        f16x4 hv = {ha, hb, hc, hd};
        f16x4 lv = {(_Float16)(a - (float)ha), (_Float16)(b - (float)hb),
                    (_Float16)(c - (float)hc), (_Float16)(d - (float)hd)};
        *reinterpret_cast<f16x4*>(&DH[(size_t)(n0 + no) * K + k0 + cc]) = hv;
        *reinterpret_cast<f16x4*>(&DL[(size_t)(n0 + no) * K + k0 + cc]) = lv;
    }
}

// fp32 -> f16 hi/lo planes (for x)
__global__ __launch_bounds__(256)
void xsplit(const float4* __restrict__ src, f16x4* __restrict__ dh,
            f16x4* __restrict__ dl)
{
    const int i = blockIdx.x * 256 + threadIdx.x;
    const float4 v = src[i];
    const _Float16 h0 = (_Float16)v.x, h1 = (_Float16)v.y;
    const _Float16 h2 = (_Float16)v.z, h3 = (_Float16)v.w;
    f16x4 hv = {h0, h1, h2, h3};
    f16x4 lv = {(_Float16)(v.x - (float)h0), (_Float16)(v.y - (float)h1),
                (_Float16)(v.z - (float)h2), (_Float16)(v.w - (float)h3)};
    dh[i] = hv; dl[i] = lv;
}

// ---------------------------------------------------------------------------
// Split-f16 MFMA GEMM. BM=BN=128, BK=32, 512 thr = 8 waves (2 row x 4 col),
// wave tile 64x32 (MF=4, NF=2), 16x16x32 frags (r3's conflict-free pattern).
// Ring-2 LDS (64 KB static), counted vmcnt: stage t+2 issued at tail of t,
// waited (vmcnt 4) at top of t -> one full iteration of latency slack.
// MODE 0: relu, split-f16 planes out via packed-LDS bounce (coalesced)
// MODE 1: fp32 out + fused per-row SSE partials vs Xin -> rec16[16][B]
// MODE 2: heads: W is concat mu|lv [128,Ka]; cols<64 -> Cf(mu), else Cf1(lv)
// ---------------------------------------------------------------------------
template<int MODE>
__global__ __launch_bounds__(512, 4)
void gemm5(const _Float16* __restrict__ Ah, const _Float16* __restrict__ Al,
           const _Float16* __restrict__ Wh, const _Float16* __restrict__ Wl,
           const float* __restrict__ bias0, const float* __restrict__ bias1,
           float* __restrict__ Cf, _Float16* __restrict__ Ch,
           _Float16* __restrict__ Cl, float* __restrict__ Cf1,
           const float* __restrict__ Xin, float* __restrict__ rec16,
           int Ka)
{
    constexpr int nY = (MODE == 2) ? 1 : 4;       // col-blocks
    __shared__ __align__(16) _Float16 sbuf[2][16384];   // [Ah|Al|Wh|Wl] x 4096

    // bijective XCD swizzle (grid % 8 == 0), bx-major so by-siblings share L2
    int wg = blockIdx.x;
    wg = (wg & 7) * (gridDim.x >> 3) + (wg >> 3);
    const int bx = wg / nY;
    const int by = wg % nY;

    const int tid  = threadIdx.x;
    const int lane = tid & 63;
    const int wid  = tid >> 6;
    const int wr = wid >> 2;          // 0..1
    const int wc = wid & 3;           // 0..3
    const int row0 = bx * 128;
    const int col0 = by * 128;

    f32x4 acc[4][2];
    #pragma unroll
    for (int i = 0; i < 4; ++i)
        #pragma unroll
        for (int j = 0; j < 2; ++j) acc[i][j] = {0.f, 0.f, 0.f, 0.f};

    const int clane = lane >> 2;      // row within 16-row chunk
    const int cslot = lane & 3;

    // 32 chunks: q<8 Ah, <16 Al, <24 Wh, else Wl; 4 per wave
    #define STAGE(buf, kk0)                                                   \
    {                                                                         \
        _Pragma("unroll")                                                     \
        for (int p = 0; p < 4; ++p) {                                         \
            const int q  = wid * 4 + p;                                       \
            const int ch = q & 7;                                             \
            const int rl = ch * 16 + clane;                                   \
            const int cs = cslot ^ ((rl >> 1) & 3);                           \
            const bool isA = q < 16;                                          \
            const size_t gi = (size_t)((isA ? row0 : col0) + rl) * Ka         \
                              + (kk0) + cs * 8;                               \
            const _Float16* gp = (q < 8) ? (Ah + gi) : (q < 16) ? (Al + gi)   \
                               : (q < 24) ? (Wh + gi) : (Wl + gi);            \
            GLL16(gp, &sbuf[buf][q * 512]);                                   \
        }                                                                     \
    }

    const int NT = Ka >> 5;
    STAGE(0, 0)
    if (NT > 1) STAGE(1, 32)

    for (int t = 0; t < NT; ++t) {
        if (t + 1 < NT) { asm volatile("s_waitcnt vmcnt(4)" ::: "memory"); }
        else            { asm volatile("s_waitcnt vmcnt(0)" ::: "memory"); }
        __builtin_amdgcn_s_barrier();
        asm volatile("" ::: "memory");

        const _Float16* Sb = sbuf[t & 1];
        f16x8 fah[4], fal[4], fwh[2], fwl[2];
        #pragma unroll
        for (int mf = 0; mf < 4; ++mf) {
            const int r = wr * 64 + mf * 16 + (lane & 15);
            const int u = (lane >> 4) ^ ((r >> 1) & 3);
            fah[mf] = *reinterpret_cast<const f16x8*>(&Sb[r * 32 + u * 8]);
            fal[mf] = *reinterpret_cast<const f16x8*>(&Sb[4096 + r * 32 + u * 8]);
        }
        #pragma unroll
        for (int nf = 0; nf < 2; ++nf) {
            const int r = wc * 32 + nf * 16 + (lane & 15);
            const int u = (lane >> 4) ^ ((r >> 1) & 3);
            fwh[nf] = *reinterpret_cast<const f16x8*>(&Sb[8192 + r * 32 + u * 8]);
            fwl[nf] = *reinterpret_cast<const f16x8*>(&Sb[12288 + r * 32 + u * 8]);
        }
        __builtin_amdgcn_s_setprio(1);
        #pragma unroll
        for (int mf = 0; mf < 4; ++mf)
            #pragma unroll
            for (int nf = 0; nf < 2; ++nf) {
                acc[mf][nf] = __builtin_amdgcn_mfma_f32_16x16x32_f16(
                    fah[mf], fwh[nf], acc[mf][nf], 0, 0, 0);
                acc[mf][nf] = __builtin_amdgcn_mfma_f32_16x16x32_f16(
                    fah[mf], fwl[nf], acc[mf][nf], 0, 0, 0);
                acc[mf][nf] = __builtin_amdgcn_mfma_f32_16x16x32_f16(
                    fal[mf], fwh[nf], acc[mf][nf], 0, 0, 0);
            }
        __builtin_amdgcn_s_setprio(0);

        asm volatile("" ::: "memory");
        __builtin_amdgcn_s_barrier();
        asm volatile("" ::: "memory");
        if (t + 2 < NT) STAGE((t & 1), (t + 2) * 32)
    }
    #undef STAGE

    // ---------------- epilogue ----------------
    if (MODE == 0) {
        // pack (hi|lo) u32 into LDS bounce, then coalesced plane copy-out
        uint32_t* sb32 = reinterpret_cast<uint32_t*>(&sbuf[0][0]);
        #pragma unroll
        for (int nf = 0; nf < 2; ++nf) {
            const int cl = wc * 32 + nf * 16 + (lane & 15);
            const float bv = bias0[col0 + cl];
            #pragma unroll
            for (int mf = 0; mf < 4; ++mf)
                #pragma unroll
                for (int j = 0; j < 4; ++j) {
                    const int rl = wr * 64 + mf * 16 + (lane >> 4) * 4 + j;
                    float v = fmaxf(acc[mf][nf][j] + bv, 0.f);
                    const _Float16 h = (_Float16)v;
                    const _Float16 l = (_Float16)(v - (float)h);
                    const uint32_t pk = (uint32_t)__builtin_bit_cast(uint16_t, h)
                                      | ((uint32_t)__builtin_bit_cast(uint16_t, l) << 16);
                    sb32[rl * 128 + cl] = pk;
                }
        }
        asm volatile("" ::: "memory");
        __builtin_amdgcn_s_barrier();
        asm volatile("" ::: "memory");
        #pragma unroll
        for (int i = 0; i < 8; ++i) {
            const int rl = i * 16 + (tid >> 5);
            const int c4 = (tid & 31) * 4;
            uint32_t w0 = sb32[rl * 128 + c4 + 0];
            uint32_t w1 = sb32[rl * 128 + c4 + 1];
            uint32_t w2 = sb32[rl * 128 + c4 + 2];
            uint32_t w3 = sb32[rl * 128 + c4 + 3];
            f16x4 hv = {__builtin_bit_cast(_Float16, (uint16_t)(w0 & 0xffff)),
                        __builtin_bit_cast(_Float16, (uint16_t)(w1 & 0xffff)),
                        __builtin_bit_cast(_Float16, (uint16_t)(w2 & 0xffff)),
                        __builtin_bit_cast(_Float16, (uint16_t)(w3 & 0xffff))};
            f16x4 lv = {__builtin_bit_cast(_Float16, (uint16_t)(w0 >> 16)),
                        __builtin_bit_cast(_Float16, (uint16_t)(w1 >> 16)),
                        __builtin_bit_cast(_Float16, (uint16_t)(w2 >> 16)),
                        __builtin_bit_cast(_Float16, (uint16_t)(w3 >> 16))};
            const size_t o = (size_t)(row0 + rl) * 512 + col0 + c4;
            *reinterpret_cast<f16x4*>(&Ch[o]) = hv;
            *reinterpret_cast<f16x4*>(&Cl[o]) = lv;
        }
    } else if (MODE == 1) {
        float rsum[4][4];
        #pragma unroll
        for (int mf = 0; mf < 4; ++mf)
            #pragma unroll
            for (int j = 0; j < 4; ++j) rsum[mf][j] = 0.f;
        #pragma unroll
        for (int nf = 0; nf < 2; ++nf) {
            const int col = col0 + wc * 32 + nf * 16 + (lane & 15);
            const float bv = bias0[col];
            #pragma unroll
            for (int mf = 0; mf < 4; ++mf)
                #pragma unroll
                for (int j = 0; j < 4; ++j) {
                    const int row = row0 + wr * 64 + mf * 16 + (lane >> 4) * 4 + j;
                    const float v = acc[mf][nf][j] + bv;
                    Cf[(size_t)row * 512 + col] = v;
                    const float d = v - Xin[(size_t)row * 512 + col];
                    rsum[mf][j] += d * d;
                }
        }
        #pragma unroll
        for (int mf = 0; mf < 4; ++mf)
            #pragma unroll
            for (int j = 0; j < 4; ++j) {
                float s = rsum[mf][j];
                s += __shfl_xor(s, 1); s += __shfl_xor(s, 2);
                s += __shfl_xor(s, 4); s += __shfl_xor(s, 8);
                if ((lane & 15) == 0) {
                    const int row = row0 + wr * 64 + mf * 16 + (lane >> 4) * 4 + j;
                    rec16[(size_t)(by * 4 + wc) * Bb + row] = s;
                }
            }
    } else {  // MODE 2: heads, cols<64 -> mu (Cf), else lv (Cf1)
        #pragma unroll
        for (int nf = 0; nf < 2; ++nf) {
            const int col = wc * 32 + nf * 16 + (lane & 15);   // 0..127
            const float bv = (col < 64) ? bias0[col] : bias1[col - 64];
            #pragma unroll
            for (int mf = 0; mf < 4; ++mf)
                #pragma unroll
                for (int j = 0; j < 4; ++j) {
                    const int row = row0 + wr * 64 + mf * 16 + (lane >> 4) * 4 + j;
                    const float v = acc[mf][nf][j] + bv;
                    if (col < 64) Cf [(size_t)row * 64 + col]      = v;
                    else          Cf1[(size_t)row * 64 + col - 64] = v;
                }
        }
    }
}

// z = mu + exp(0.5*logvar)*eps -> split f16 planes
__global__ __launch_bounds__(256)
void z_kernel(const float4* __restrict__ mu, const float4* __restrict__ lv,
              const float4* __restrict__ eps, f16x4* __restrict__ zh,
              f16x4* __restrict__ zl)
{
    const int i = blockIdx.x * 256 + threadIdx.x;
    const float4 m = mu[i], l = lv[i], e = eps[i];
    float4 r;
    r.x = m.x + expf(0.5f * l.x) * e.x;
    r.y = m.y + expf(0.5f * l.y) * e.y;
    r.z = m.z + expf(0.5f * l.z) * e.z;
    r.w = m.w + expf(0.5f * l.w) * e.w;
    const _Float16 h0 = (_Float16)r.x, h1 = (_Float16)r.y;
    const _Float16 h2 = (_Float16)r.z, h3 = (_Float16)r.w;
    f16x4 hv = {h0, h1, h2, h3};
    f16x4 lvv = {(_Float16)(r.x - (float)h0), (_Float16)(r.y - (float)h1),
                 (_Float16)(r.z - (float)h2), (_Float16)(r.w - (float)h3)};
    zh[i] = hv; zl[i] = lvv;
}

// sum 16 partials, running-min select + gather
__global__ __launch_bounds__(256)
void select_kernel(const float* __restrict__ rec16, float* __restrict__ best,
                   const float* __restrict__ mu_e, const float* __restrict__ lv_e,
                   const float* __restrict__ xhat,
                   float* __restrict__ out_mu, float* __restrict__ out_lv,
                   float* __restrict__ out_xh, int isFirst)
{
    const int wave = threadIdx.x >> 6;
    const int lane = threadIdx.x & 63;
    const int row  = blockIdx.x * 4 + wave;
    float r = 0.f;
    #pragma unroll
    for (int p = 0; p < 16; ++p) r += rec16[(size_t)p * Bb + row];
    r *= (1.0f / 512.0f);
    const bool cond = isFirst || (r < best[row]);
    if (cond) {
        if (lane == 0) best[row] = r;
        out_mu[(size_t)row * Zz + lane] = mu_e[(size_t)row * Zz + lane];
        out_lv[(size_t)row * Zz + lane] = lv_e[(size_t)row * Zz + lane];
        const float4* src = reinterpret_cast<const float4*>(&xhat[(size_t)row * Dd]);
        float4*       dst = reinterpret_cast<float4*>(&out_xh[(size_t)row * Dd]);
        dst[lane]      = src[lane];
        dst[lane + 64] = src[lane + 64];
    }
}

extern "C" void kernel_launch(void* const* d_in, const int* in_sizes, int n_in,
                              void* d_out, int out_size, void* d_ws, size_t ws_size,
                              hipStream_t stream)
{
    const float* x         = (const float*)d_in[0];
    const float* eps       = (const float*)d_in[1];
    const float* enc_in_w  = (const float*)d_in[2];
    const float* enc_in_b  = (const float*)d_in[3];
    const float* enc_hid_w = (const float*)d_in[4];
    const float* enc_hid_b = (const float*)d_in[5];
    const float* mu_w      = (const float*)d_in[6];
    const float* mu_b      = (const float*)d_in[7];
    const float* lv_w      = (const float*)d_in[8];
    const float* lv_b      = (const float*)d_in[9];
    const float* dec_in_w  = (const float*)d_in[10];
    const float* dec_in_b  = (const float*)d_in[11];
    const float* dec_hid_w = (const float*)d_in[12];
    const float* dec_hid_b = (const float*)d_in[13];
    const float* dec_out_w = (const float*)d_in[14];
    const float* dec_out_b = (const float*)d_in[15];

    const size_t BD = (size_t)Bb * 512;
    const size_t BZ = (size_t)Bb * 64;

    _Float16* wtH = (_Float16*)d_ws;
    _Float16* wtL = wtH + WT_ELEMS;
    _Float16* xh  = wtL + WT_ELEMS;
    _Float16* xl  = xh + BD;
    _Float16* aH  = xl + BD;
    _Float16* aL  = aH + BD;
    _Float16* bH  = aL + BD;
    _Float16* bL  = bH + BD;
    _Float16* zh  = bL + BD;
    _Float16* zl  = zh + BZ;
    float* fbase  = (float*)(zl + BZ);
    float* xhat   = fbase;                  // [B,512] fp32
    float* mu_e   = xhat + BD;
    float* lv_e   = mu_e + BZ;
    float* rec16  = lv_e + BZ;              // [16,B]
    float* best   = rec16 + (size_t)16 * Bb;

    float* out_mu = (float*)d_out;
    float* out_lv = out_mu + (size_t)Bb * Zz;
    float* out_xh = out_lv + (size_t)Bb * Zz;

    const dim3 blk(256);

    tsplit<<<dim3(8, 8, 8), blk, 0, stream>>>(enc_in_w,           wtH + OFF_ENCIN,  wtL + OFF_ENCIN,  512, 512, 262144, PEREXP);
    tsplit<<<dim3(8, 8, 8), blk, 0, stream>>>(enc_hid_w,          wtH + OFF_HID0,   wtL + OFF_HID0,   512, 512, 524288, PEREXP);
    tsplit<<<dim3(8, 8, 8), blk, 0, stream>>>(enc_hid_w + 262144, wtH + OFF_HID1,   wtL + OFF_HID1,   512, 512, 524288, PEREXP);
    tsplit<<<dim3(1, 8, 8), blk, 0, stream>>>(mu_w,               wtH + OFF_MU,     wtL + OFF_MU,     512,  64,  32768, PEREXP);
    tsplit<<<dim3(1, 8, 8), blk, 0, stream>>>(lv_w,               wtH + OFF_LV,     wtL + OFF_LV,     512,  64,  32768, PEREXP);
    tsplit<<<dim3(8, 1, 8), blk, 0, stream>>>(dec_in_w,           wtH + OFF_DECIN,  wtL + OFF_DECIN,   64, 512,  32768, PEREXP);
    tsplit<<<dim3(8, 8, 8), blk, 0, stream>>>(dec_hid_w,          wtH + OFF_DHID0,  wtL + OFF_DHID0,  512, 512, 524288, PEREXP);
    tsplit<<<dim3(8, 8, 8), blk, 0, stream>>>(dec_hid_w + 262144, wtH + OFF_DHID1,  wtL + OFF_DHID1,  512, 512, 524288, PEREXP);
    tsplit<<<dim3(8, 8, 8), blk, 0, stream>>>(dec_out_w,          wtH + OFF_DECOUT, wtL + OFF_DECOUT, 512, 512, 262144, PEREXP);
    xsplit<<<dim3(BD / 4 / 256), blk, 0, stream>>>(
        (const float4*)x, (f16x4*)xh, (f16x4*)xl);

    const dim3 gblk(512);
    const dim3 gBig(512);     // 128 bx * 4 by
    const dim3 gHead(128);    // 128 bx * 1
    const dim3 gRow(Bb / 4);
    const dim3 gZ(BZ / 4 / 256);

    for (int e = 0; e < Eexp; ++e) {
        const size_t wo = (size_t)e * PEREXP;
        gemm5<0><<<gBig, gblk, 0, stream>>>(
            xh, xl, wtH + wo + OFF_ENCIN, wtL + wo + OFF_ENCIN,
            enc_in_b + (size_t)e * Hh, nullptr,
            nullptr, aH, aL, nullptr, nullptr, nullptr, Dd);
        gemm5<0><<<gBig, gblk, 0, stream>>>(
            aH, aL, wtH + wo + OFF_HID0, wtL + wo + OFF_HID0,
            enc_hid_b + ((size_t)e * 2 + 0) * Hh, nullptr,
            nullptr, bH, bL, nullptr, nullptr, nullptr, Hh);
        gemm5<0><<<gBig, gblk, 0, stream>>>(
            bH, bL, wtH + wo + OFF_HID1, wtL + wo + OFF_HID1,
            enc_hid_b + ((size_t)e * 2 + 1) * Hh, nullptr,
            nullptr, aH, aL, nullptr, nullptr, nullptr, Hh);
        gemm5<2><<<gHead, gblk, 0, stream>>>(
            aH, aL, wtH + wo + OFF_MU, wtL + wo + OFF_MU,
            mu_b + (size_t)e * Zz, lv_b + (size_t)e * Zz,
            mu_e, nullptr, nullptr, lv_e, nullptr, nullptr, Hh);
        z_kernel<<<gZ, blk, 0, stream>>>(
            (const float4*)mu_e, (const float4*)lv_e, (const float4*)eps,
            (f16x4*)zh, (f16x4*)zl);
        gemm5<0><<<gBig, gblk, 0, stream>>>(
            zh, zl, wtH + wo + OFF_DECIN, wtL + wo + OFF_DECIN,
            dec_in_b + (size_t)e * Hh, nullptr,
            nullptr, bH, bL, nullptr, nullptr, nullptr, Zz);
        gemm5<0><<<gBig, gblk, 0, stream>>>(
            bH, bL, wtH + wo + OFF_DHID0, wtL + wo + OFF_DHID0,
            dec_hid_b + ((size_t)e * 2 + 0) * Hh, nullptr,
            nullptr, aH, aL, nullptr, nullptr, nullptr, Hh);
        gemm5<0><<<gBig, gblk, 0, stream>>>(
            aH, aL, wtH + wo + OFF_DHID1, wtL + wo + OFF_DHID1,
            dec_hid_b + ((size_t)e * 2 + 1) * Hh, nullptr,
            nullptr, bH, bL, nullptr, nullptr, nullptr, Hh);
        gemm5<1><<<gBig, gblk, 0, stream>>>(
            bH, bL, wtH + wo + OFF_DECOUT, wtL + wo + OFF_DECOUT,
            dec_out_b + (size_t)e * Dd, nullptr,
            xhat, nullptr, nullptr, nullptr, x, rec16, Hh);
        select_kernel<<<gRow, blk, 0, stream>>>(
            rec16, best, mu_e, lv_e, xhat, out_mu, out_lv, out_xh, e == 0 ? 1 : 0);
    }
}